// Round 17
// baseline (150.284 us; speedup 1.0000x reference)
//
#include <hip/hip_runtime.h>
#include <hip/hip_bf16.h>

// Sizes (fixed by the problem)
#define B_   2
#define LQ_  2048
#define LK_  2048
#define QDIM_ 1024
#define KDIM_ 768
#define VDIM_ 768
#define HID_ 1024
#define H_   16
#define D_   64   // head dim

typedef unsigned short ushort_t;
typedef __attribute__((ext_vector_type(8))) short short8v;   // 8 bf16 MFMA A/B frag
typedef __attribute__((ext_vector_type(4))) float f32x4;     // MFMA C/D frag

__device__ __forceinline__ float bf2f(unsigned short u) {
    union { unsigned int i; float f; } x; x.i = ((unsigned int)u) << 16; return x.f;
}
__device__ __forceinline__ unsigned short f2bf(float f) {
    union { float f; unsigned int i; } x; x.f = f;
    unsigned int r = x.i + 0x7FFFu + ((x.i >> 16) & 1u);  // RNE
    return (unsigned short)(r >> 16);
}
__device__ __forceinline__ float exp2_(float x) {
#if defined(__has_builtin) && __has_builtin(__builtin_amdgcn_exp2f)
    return __builtin_amdgcn_exp2f(x);
#else
    return __expf(x * 0.69314718055994531f);
#endif
}
__device__ __forceinline__ unsigned cvtpk_bf16(float lo, float hi) {
    unsigned r;
    asm("v_cvt_pk_bf16_f32 %0, %1, %2" : "=v"(r) : "v"(lo), "v"(hi));
    return r;
}
__device__ __forceinline__ unsigned perm_b32(unsigned hi, unsigned lo, unsigned sel) {
#if defined(__has_builtin) && __has_builtin(__builtin_amdgcn_perm)
    return __builtin_amdgcn_perm(hi, lo, sel);
#else
    unsigned r = 0;
    for (int i = 0; i < 4; ++i) {
        unsigned s = (sel >> (8 * i)) & 0xFF;
        unsigned byte = (s < 4) ? ((lo >> (8 * s)) & 0xFF) : ((hi >> (8 * (s - 4))) & 0xFF);
        r |= byte << (8 * i);
    }
    return r;
#endif
}
// global -> LDS direct (16B per lane). Fallback: plain copy.
__device__ __forceinline__ void stage16(const ushort_t* g, ushort_t* l) {
#if defined(__has_builtin) && __has_builtin(__builtin_amdgcn_global_load_lds)
    __builtin_amdgcn_global_load_lds(
        (const __attribute__((address_space(1))) unsigned*)g,
        (__attribute__((address_space(3))) unsigned*)l, 16, 0, 0);
#else
    *(uint4*)l = *(const uint4*)g;
#endif
}

// ---------------------------------------------------------------------------
// Inline dtype detection (1 -> inputs bf16, 0 -> f32). All threads read the
// SAME 64 half-words of `query` (broadcast loads) -> block-uniform result.
// ---------------------------------------------------------------------------
__device__ __forceinline__ int detect_isbf(const ushort_t* __restrict__ q) {
    float m = 0.f;
    #pragma unroll
    for (int i = 0; i < 8; ++i) {
        uint4 v = *(const uint4*)(q + i * 8);
        const ushort_t* p = (const ushort_t*)&v;
        #pragma unroll
        for (int j = 0; j < 8; ++j) m = fmaxf(m, fabsf(bf2f(p[j])));
    }
    return m < 1000.0f ? 1 : 0;
}

// ---------------------------------------------------------------------------
// Fused 4-way transpose, 64x64 tiles, vectorized in AND out.
// op z: W[R][1024] (f32/bf16 by detection) -> WT[1024][R] bf16.
// ops: 0=Wq(R=1024) 1=Wk(768) 2=Wv(768) 3=Wo(1024)
// ---------------------------------------------------------------------------
__global__ __launch_bounds__(256) void transpose4(
    const void* __restrict__ W0, const void* __restrict__ W1,
    const void* __restrict__ W2, const void* __restrict__ W3,
    ushort_t* __restrict__ O0, ushort_t* __restrict__ O1,
    ushort_t* __restrict__ O2, ushort_t* __restrict__ O3,
    const ushort_t* __restrict__ qdet)
{
    __shared__ ushort_t tile[64][72];   // 144B rows: b128 writes aligned
    const int isbf = detect_isbf(qdet);
    const int op = blockIdx.z;
    const void* in = (op == 0) ? W0 : (op == 1) ? W1 : (op == 2) ? W2 : W3;
    ushort_t* out  = (op == 0) ? O0 : (op == 1) ? O1 : (op == 2) ? O2 : O3;
    const int R = (op == 1 || op == 2) ? KDIM_ : 1024;
    const int C = 1024;
    const int r0 = blockIdx.y * 64, c0 = blockIdx.x * 64;
    if (r0 >= R) return;
    const int tr = threadIdx.x >> 3;          // 0..31
    const int tc8 = (threadIdx.x & 7) * 8;    // 0..56

    #pragma unroll
    for (int h = 0; h < 2; ++h) {             // rows tr, tr+32
        int r = r0 + tr + h * 32;
        ushort_t tmp[8];
        if (isbf) {
            *(uint4*)tmp = *(const uint4*)((const ushort_t*)in + (size_t)r * C + c0 + tc8);
        } else {
            const float* f = (const float*)in + (size_t)r * C + c0 + tc8;
            float4 a = *(const float4*)f;
            float4 b2 = *(const float4*)(f + 4);
            tmp[0]=f2bf(a.x);  tmp[1]=f2bf(a.y);  tmp[2]=f2bf(a.z);  tmp[3]=f2bf(a.w);
            tmp[4]=f2bf(b2.x); tmp[5]=f2bf(b2.y); tmp[6]=f2bf(b2.z); tmp[7]=f2bf(b2.w);
        }
        *(uint4*)&tile[tr + h * 32][tc8] = *(uint4*)tmp;
    }
    __syncthreads();
    #pragma unroll
    for (int h = 0; h < 2; ++h) {             // out cols tr, tr+32; rows tc8..+7
        int c = tr + h * 32;
        ushort_t tmp[8];
        #pragma unroll
        for (int j = 0; j < 8; ++j) tmp[j] = tile[tc8 + j][c];
        *(uint4*)(out + (size_t)(c0 + c) * R + r0 + tc8) = *(uint4*)tmp;
    }
}

// ---------------------------------------------------------------------------
// GEMM core, 2-phase double-buffered, tile 128xTBN, BK=32, 256 thr = 4 waves
// (2x2), wave tile 64x(TBN/2). LDS XOR-swizzled (row&3 on 8-col chunks):
// pre-swizzled gload_lds source, swizzled reads.
// ---------------------------------------------------------------------------
template<int TBN>
__device__ __forceinline__ void gemm_core(
    const void* __restrict__ A, const ushort_t* __restrict__ WT,
    const void* __restrict__ bias, void* __restrict__ Cp,
    int M, int N, int K, int isbf, int a_bf, int c_bf, float out_scale,
    int wg, ushort_t (*As)[32], ushort_t (*Bs)[32])
{
    constexpr int NF = TBN / 32;              // B frags per wave
    const int tid = threadIdx.x;
    const int l = tid & 63, w = tid >> 6;
    const int g = l >> 4, q = l & 15;
    const int wr = (w >> 1) * 64, wc = (w & 1) * (TBN / 2);
    const int nbn = N / TBN;
    const int bm = (wg / nbn) * 128;
    const int bn = (wg % nbn) * TBN;

    const int r_ = tid >> 2;                    // 0..63
    const int c_ = tid & 3;                     // 8-col chunk
    const int sc_ = ((c_ ^ (r_ & 3)) << 3);     // swizzled col
    const int dc_ = c_ << 3;

    f32x4 acc[4][NF];
    #pragma unroll
    for (int i = 0; i < 4; ++i)
        #pragma unroll
        for (int j = 0; j < NF; ++j)
            acc[i][j] = (f32x4){0.f, 0.f, 0.f, 0.f};

    const int NT = K >> 5;
    float4 fA[4];

    auto issue = [&](int t, int buf) {
        const int koff = t << 5;
        if (a_bf) {
            stage16((const ushort_t*)A + (size_t)(bm + r_) * K + koff + sc_,
                    &As[(buf << 7) + r_][dc_]);
            stage16((const ushort_t*)A + (size_t)(bm + 64 + r_) * K + koff + sc_,
                    &As[(buf << 7) + 64 + r_][dc_]);
        } else {
            const float* Af0 = (const float*)A + (size_t)(bm + r_) * K + koff + dc_;
            const float* Af1 = (const float*)A + (size_t)(bm + 64 + r_) * K + koff + dc_;
            fA[0] = *(const float4*)Af0; fA[1] = *(const float4*)(Af0 + 4);
            fA[2] = *(const float4*)Af1; fA[3] = *(const float4*)(Af1 + 4);
        }
        stage16(WT + (size_t)(bn + r_) * K + koff + sc_, &Bs[buf * TBN + r_][dc_]);
        if (TBN == 128)
            stage16(WT + (size_t)(bn + 64 + r_) * K + koff + sc_, &Bs[buf * TBN + 64 + r_][dc_]);
    };
    auto commitA = [&](int buf) {
        ushort_t t0[8], t1[8];
        t0[0]=f2bf(fA[0].x); t0[1]=f2bf(fA[0].y); t0[2]=f2bf(fA[0].z); t0[3]=f2bf(fA[0].w);
        t0[4]=f2bf(fA[1].x); t0[5]=f2bf(fA[1].y); t0[6]=f2bf(fA[1].z); t0[7]=f2bf(fA[1].w);
        t1[0]=f2bf(fA[2].x); t1[1]=f2bf(fA[2].y); t1[2]=f2bf(fA[2].z); t1[3]=f2bf(fA[2].w);
        t1[4]=f2bf(fA[3].x); t1[5]=f2bf(fA[3].y); t1[6]=f2bf(fA[3].z); t1[7]=f2bf(fA[3].w);
        *(uint4*)&As[(buf << 7) + r_][sc_]      = *(uint4*)t0;
        *(uint4*)&As[(buf << 7) + 64 + r_][sc_] = *(uint4*)t1;
    };

    issue(0, 0);
    if (!a_bf) commitA(0);
    __syncthreads();

    int cur = 0;
    const int fcol = ((g ^ (q & 3)) << 3);   // frag read col (swizzled)
    for (int t = 0; t < NT; ++t) {
        const bool has = (t + 1 < NT);
        if (has) issue(t + 1, cur ^ 1);

        short8v a[4], bb[NF];
        #pragma unroll
        for (int mf = 0; mf < 4; ++mf)
            a[mf] = *(const short8v*)&As[(cur << 7) + wr + mf * 16 + q][fcol];
        #pragma unroll
        for (int nf = 0; nf < NF; ++nf)
            bb[nf] = *(const short8v*)&Bs[cur * TBN + wc + nf * 16 + q][fcol];
        #pragma unroll
        for (int mf = 0; mf < 4; ++mf)
            #pragma unroll
            for (int nf = 0; nf < NF; ++nf)
                acc[mf][nf] = __builtin_amdgcn_mfma_f32_16x16x32_bf16(a[mf], bb[nf], acc[mf][nf], 0, 0, 0);

        if (has && !a_bf) commitA(cur ^ 1);
        __syncthreads();
        cur ^= 1;
    }

    // epilogue: D layout col=lane&15, row=(lane>>4)*4+reg
    float bv[NF];
    #pragma unroll
    for (int nf = 0; nf < NF; ++nf) {
        int col = bn + wc + nf * 16 + q;
        bv[nf] = isbf ? bf2f(((const ushort_t*)bias)[col]) : ((const float*)bias)[col];
    }
    #pragma unroll
    for (int mf = 0; mf < 4; ++mf)
        #pragma unroll
        for (int nf = 0; nf < NF; ++nf)
            #pragma unroll
            for (int reg = 0; reg < 4; ++reg) {
                int row = bm + wr + mf * 16 + g * 4 + reg;
                int col = bn + wc + nf * 16 + q;
                float vv = (acc[mf][nf][reg] + bv[nf]) * out_scale;
                if (c_bf) ((ushort_t*)Cp)[(size_t)row * N + col] = f2bf(vv);
                else      ((float*)Cp)[(size_t)row * N + col] = vv;
            }
}

struct G3 {
    const void* A0; const void* A1; const void* A2;
    const ushort_t* W0; const ushort_t* W1; const ushort_t* W2;
    const void* b0; const void* b1; const void* b2;
    void* C0; void* C1; void* C2;
    int K0, K1, K2;
    float s0, s1, s2;
};

// fused Q/K/V projections: grid (256, 3); blockIdx.y picks the op
__global__ __launch_bounds__(256) void gemm3_mfma(G3 p, int M, int N,
                                                  const ushort_t* __restrict__ qdet)
{
    __shared__ ushort_t As[2 * 128][32];
    __shared__ ushort_t Bs[2 * 128][32];
    const int isbf = detect_isbf(qdet);
    const int op = blockIdx.y;
    const void* A = (op == 0) ? p.A0 : (op == 1) ? p.A1 : p.A2;
    const ushort_t* WT = (op == 0) ? p.W0 : (op == 1) ? p.W1 : p.W2;
    const void* bias = (op == 0) ? p.b0 : (op == 1) ? p.b1 : p.b2;
    void* C = (op == 0) ? p.C0 : (op == 1) ? p.C1 : p.C2;
    const int K = (op == 0) ? p.K0 : (op == 1) ? p.K1 : p.K2;
    const float sc = (op == 0) ? p.s0 : (op == 1) ? p.s1 : p.s2;
    const int cpx = gridDim.x >> 3;
    const int wg = (blockIdx.x & 7) * cpx + (blockIdx.x >> 3);
    gemm_core<128>(A, WT, bias, C, M, N, K, isbf, isbf, 1, sc, wg, As, Bs);
}

// O-projection: tile 128x64 -> 512 blocks = 2 blocks/CU
__global__ __launch_bounds__(256) void gemm_one(
    const void* __restrict__ A, const ushort_t* __restrict__ WT,
    const void* __restrict__ bias, void* __restrict__ Cp,
    int M, int N, int K, const ushort_t* __restrict__ qdet, float out_scale)
{
    __shared__ ushort_t As[2 * 128][32];
    __shared__ ushort_t Bs[2 * 64][32];
    const int isbf = detect_isbf(qdet);
    const int cpx = gridDim.x >> 3;
    const int wg = (blockIdx.x & 7) * cpx + (blockIdx.x >> 3);
    gemm_core<64>(A, WT, bias, Cp, M, N, K, isbf, 1, isbf, out_scale, wg, As, Bs);
}

// ---------------------------------------------------------------------------
// MFMA flash attention, 32 q-rows PER WAVE (2 q-sets share every K/V LDS
// fragment read -> per-q-row LDS/L2 traffic halves vs r16). 512 thr = 8
// waves; block = 256 q-rows; 256 blocks (1/CU); KV tiles 64, double-buffered
// (K 1-ahead via gload_lds, V issue-early/write-late regs). 1-D XCD-chunked
// grid: each XCD owns 4 whole (b,h) groups -> K/V L2-resident, and only 8
// blocks re-read each (b,h)'s K/V (was 16). Swapped S^T = K.Q^T; PV O^T =
// V^T.P^T (lane-local softmax rows; lane owns rows mqb and mqb+128).
// Masking via packed-halfword AND on P; denominator via ones-A-frag MFMA.
// Q pre-scaled by 0.125*log2(e). ctx written IN-PLACE over Q.
// query_mask masks the KEY axis; key_mask masks the QUERY axis (faithful).
// ---------------------------------------------------------------------------
__global__ __launch_bounds__(512) void attn_mfma(
    const ushort_t* __restrict__ Q, const ushort_t* __restrict__ Kp,
    const ushort_t* __restrict__ Vp, const int* __restrict__ qmask,
    const int* __restrict__ kmask, ushort_t* __restrict__ ctx)   // ctx may alias Q
{
    __shared__ ushort_t sK[2][64][64];
    __shared__ ushort_t sVt[2][64][64];   // [d][key], swizzled
    __shared__ ushort_t sP[8][32][64];    // per-wave P, 2 q-sets, swizzled
    __shared__ unsigned sMaskAll[32][32]; // per-tile packed halfword masks

    const int tid = threadIdx.x;
    const int l = tid & 63, w = tid >> 6;   // 8 waves
    const int g = l >> 4, q = l & 15;
    // 256 blocks: XCD x owns wg in [32x, 32x+32) = 4 whole (b,h) groups.
    const int wg = ((int)blockIdx.x & 7) * 32 + ((int)blockIdx.x >> 3);
    const int grp = wg >> 3;              // (b,h) group: 0..31
    const int q0 = (wg & 7) * 256;
    const int b = grp >> 4, h = grp & 15;
    const size_t hoff = (size_t)h * 64;
    const int swz = (q & 7) << 3;

    // V staging map: 256 pair-chunks (2 keys x 8 d), split across 2 threads
    const int vpi = tid & 255;
    const int vk2 = (vpi & 31) * 2;
    const int vdb = vpi >> 5;             // 0..7
    const int vds = (tid >> 8) * 4;       // 0 or 4
    const size_t vbase0 = ((size_t)(b * LK_) + vk2) * HID_ + hoff + vdb * 8 + vds;

    const int krow = tid >> 3, ks = tid & 7;
    const int kscol = ((ks ^ (krow & 7)) << 3);
    const size_t kbase0 = ((size_t)(b * LK_) + krow) * HID_ + hoff + kscol;

    auto writeV = [&](int buf, uint2 a, uint2 c) {
        #pragma unroll
        for (int t2 = 0; t2 < 2; ++t2) {
            unsigned d0w = t2 ? a.y : a.x;
            unsigned d1w = t2 ? c.y : c.x;
            unsigned lo = perm_b32(d1w, d0w, 0x05040100);
            unsigned hi = perm_b32(d1w, d0w, 0x07060302);
            int dr0 = vdb * 8 + vds + 2 * t2, dr1 = dr0 + 1;
            *(unsigned*)&sVt[buf][dr0][vk2 ^ ((dr0 & 7) << 3)] = lo;
            *(unsigned*)&sVt[buf][dr1][vk2 ^ ((dr1 & 7) << 3)] = hi;
        }
    };

    // ---- prologue: K/V tile 0, ALL 32 tile masks; Q direct to registers ----
    stage16(Kp + kbase0, &sK[0][krow][ks << 3]);
    {
        uint2 a = *(const uint2*)(Vp + vbase0);
        uint2 c = *(const uint2*)(Vp + vbase0 + HID_);
        writeV(0, a, c);
    }
    for (int tt = w; tt < 32; tt += 8) {   // each wave: 4 tiles' masks
        unsigned long long bits = __ballot(qmask[b * LQ_ + tt * 64 + l] != 0);
        if (l < 32) {
            unsigned dw = (((bits >> (2 * l)) & 1ull) ? 0xFFFFu : 0u)
                        | (((bits >> (2 * l + 1)) & 1ull) ? 0xFFFF0000u : 0u);
            sMaskAll[tt][l] = dw;
        }
    }

    const int mqb = 16 * w + q;           // base q-row within the 128-row half
    short8v qf[2][2];
    int rowm[2];
    #pragma unroll
    for (int s = 0; s < 2; ++s) {
        const ushort_t* Qrow = Q + ((size_t)(b * LQ_) + q0 + s * 128 + mqb) * HID_ + hoff;
        qf[s][0] = *(const short8v*)(Qrow + (g << 3));
        qf[s][1] = *(const short8v*)(Qrow + 32 + (g << 3));
        rowm[s] = kmask[b * LK_ + q0 + s * 128 + mqb];
    }
    __syncthreads();

    short8v ones;
    #pragma unroll
    for (int j = 0; j < 8; ++j) ones[j] = (short)0x3F80;   // 1.0bf16

    float m_run[2] = {-1e30f, -1e30f};
    f32x4 o[2][4], o4[2];
    #pragma unroll
    for (int s = 0; s < 2; ++s) {
        #pragma unroll
        for (int df = 0; df < 4; ++df) o[s][df] = (f32x4){0.f, 0.f, 0.f, 0.f};
        o4[s] = (f32x4){0.f, 0.f, 0.f, 0.f};
    }

    for (int t = 0; t < 32; ++t) {
        const int cur = t & 1;
        const bool hasN = (t + 1 < 32);
        uint2 va, vc;
        if (hasN) {   // issue-early: next K via gload_lds, next V to regs
            stage16(Kp + kbase0 + (size_t)(t + 1) * 64 * HID_,
                    &sK[cur ^ 1][krow][ks << 3]);
            size_t basev = vbase0 + (size_t)(t + 1) * 64 * HID_;
            va = *(const uint2*)(Vp + basev);
            vc = *(const uint2*)(Vp + basev + HID_);
        }

        // ---- S^T = K . Q^T, both q-sets share every K-frag read ----
        f32x4 S[2][4];
        #pragma unroll
        for (int s = 0; s < 2; ++s)
            #pragma unroll
            for (int kf = 0; kf < 4; ++kf) S[s][kf] = (f32x4){0.f, 0.f, 0.f, 0.f};
        __builtin_amdgcn_s_setprio(1);
        #pragma unroll
        for (int kf = 0; kf < 4; ++kf) {
            short8v k0f = *(const short8v*)&sK[cur][kf * 16 + q][(g << 3) ^ swz];
            short8v k1f = *(const short8v*)&sK[cur][kf * 16 + q][(32 + (g << 3)) ^ swz];
            #pragma unroll
            for (int s = 0; s < 2; ++s) {
                S[s][kf] = __builtin_amdgcn_mfma_f32_16x16x32_bf16(k0f, qf[s][0], S[s][kf], 0, 0, 0);
                S[s][kf] = __builtin_amdgcn_mfma_f32_16x16x32_bf16(k1f, qf[s][1], S[s][kf], 0, 0, 0);
            }
        }
        __builtin_amdgcn_s_setprio(0);

        // ---- online softmax per set (raw scores; mask applied to P) ----
        #pragma unroll
        for (int s = 0; s < 2; ++s) {
            float tmx[8];
            #pragma unroll
            for (int i = 0; i < 8; ++i)
                tmx[i] = fmaxf(S[s][i >> 2][i & 3], S[s][2 + (i >> 2)][i & 3]);
            #pragma unroll
            for (int st = 4; st >= 1; st >>= 1)
                #pragma unroll
                for (int i = 0; i < st; ++i) tmx[i] = fmaxf(tmx[i], tmx[i + st]);
            float lm = tmx[0];
            lm = fmaxf(lm, __shfl_xor(lm, 16));
            lm = fmaxf(lm, __shfl_xor(lm, 32));

            const bool fullp = __any(lm - m_run[s] > 8.0f) != 0;   // defer-max
            float mnew, corr;
            if (fullp) { mnew = fmaxf(m_run[s], lm); corr = exp2_(m_run[s] - mnew); }
            else       { mnew = m_run[s];            corr = 1.0f; }

            #pragma unroll
            for (int kf = 0; kf < 4; ++kf)
                #pragma unroll
                for (int reg = 0; reg < 4; ++reg)
                    S[s][kf][reg] = exp2_(S[s][kf][reg] - mnew);   // P in-place
            m_run[s] = mnew;

            #pragma unroll
            for (int kf = 0; kf < 4; ++kf) {
                uint2 pv;
                pv.x = cvtpk_bf16(S[s][kf][0], S[s][kf][1]);
                pv.y = cvtpk_bf16(S[s][kf][2], S[s][kf][3]);
                *(uint2*)&sP[w][s * 16 + q][(kf * 16 + g * 4) ^ swz] = pv;
            }

            if (fullp) {   // lane-local rescale (O^T layout: no shuffles)
                #pragma unroll
                for (int df = 0; df < 4; ++df)
                    #pragma unroll
                    for (int reg = 0; reg < 4; ++reg) o[s][df][reg] *= corr;
                #pragma unroll
                for (int reg = 0; reg < 4; ++reg) o4[s][reg] *= corr;
            }
        }

        // ---- PV: O^T = V^T . P_masked^T ; vb reads shared by both sets ----
        #pragma unroll
        for (int s2 = 0; s2 < 2; ++s2) {
            uint4 mk = *(const uint4*)&sMaskAll[t][s2 * 16 + g * 4];
            short8v pa[2];
            #pragma unroll
            for (int s = 0; s < 2; ++s) {
                uint4 paw = *(const uint4*)&sP[w][s * 16 + q][((s2 * 32) + (g << 3)) ^ swz];
                paw.x &= mk.x; paw.y &= mk.y; paw.z &= mk.z; paw.w &= mk.w;
                __builtin_memcpy(&pa[s], &paw, 16);
            }
            __builtin_amdgcn_s_setprio(1);
            #pragma unroll
            for (int df = 0; df < 4; ++df) {
                short8v vb = *(const short8v*)&sVt[cur][df * 16 + q][((s2 * 32) + (g << 3)) ^ swz];
                #pragma unroll
                for (int s = 0; s < 2; ++s)
                    o[s][df] = __builtin_amdgcn_mfma_f32_16x16x32_bf16(vb, pa[s], o[s][df], 0, 0, 0);
            }
            #pragma unroll
            for (int s = 0; s < 2; ++s)
                o4[s] = __builtin_amdgcn_mfma_f32_16x16x32_bf16(ones, pa[s], o4[s], 0, 0, 0);
            __builtin_amdgcn_s_setprio(0);
        }

        if (hasN) writeV(cur ^ 1, va, vc);   // write-late: V(t+1)
        __syncthreads();
    }

    // ---- epilogue: lane owns rows mqb and mqb+128; denom lane-local ----
    #pragma unroll
    for (int s = 0; s < 2; ++s) {
        const float lr = o4[s][0];
        const float lqv = (rowm[s] != 0 && lr > 0.f) ? (1.f / lr) : 0.f;
        ushort_t* orow = ctx + ((size_t)(b * LQ_) + q0 + s * 128 + mqb) * HID_ + hoff;
        #pragma unroll
        for (int df = 0; df < 4; ++df) {
            uint2 st;
            st.x = cvtpk_bf16(o[s][df][0] * lqv, o[s][df][1] * lqv);
            st.y = cvtpk_bf16(o[s][df][2] * lqv, o[s][df][3] * lqv);
            *(uint2*)(orow + df * 16 + g * 4) = st;
        }
    }
}

// ---------------------------------------------------------------------------
extern "C" void kernel_launch(void* const* d_in, const int* in_sizes, int n_in,
                              void* d_out, int out_size, void* d_ws, size_t ws_size,
                              hipStream_t stream) {
    const int* qmask = (const int*)d_in[11];
    const int* kmask = (const int*)d_in[12];
    const ushort_t* qdet = (const ushort_t*)d_in[0];   // dtype-detection source

    const size_t M = (size_t)B_ * LQ_;      // 4096
    ushort_t* qx = (ushort_t*)((char*)d_ws + 256);   // Q-proj out, then ctx (in-place)
    ushort_t* kx = qx + M * HID_;
    ushort_t* vx = kx + M * HID_;
    ushort_t* cx = vx + M * HID_;            // 4M elems: holds ALL FOUR W^T buffers
    ushort_t* WTq = cx;                      // 1M elems
    ushort_t* WTk = WTq + 1024 * 1024;       // 0.75M
    ushort_t* WTv = WTk + 1024 * 768;        // 0.75M
    ushort_t* WTo = WTv + 1024 * 768;        // 1M  (total 3.5M <= 4M)

    const float QSCALE = 0.125f * 1.4426950408889634f;  // 1/sqrt(D) * log2(e)

    // all four weight transposes in one launch (64x64 tiles, self-detecting)
    transpose4<<<dim3(16, 16, 4), 256, 0, stream>>>(
        d_in[3], d_in[5], d_in[7], d_in[9], WTq, WTk, WTv, WTo, qdet);

    G3 p;
    p.A0 = d_in[0]; p.A1 = d_in[1]; p.A2 = d_in[2];
    p.W0 = WTq;     p.W1 = WTk;     p.W2 = WTv;
    p.b0 = d_in[4]; p.b1 = d_in[6]; p.b2 = d_in[8];
    p.C0 = qx;      p.C1 = kx;      p.C2 = vx;
    p.K0 = QDIM_;   p.K1 = KDIM_;   p.K2 = VDIM_;
    p.s0 = QSCALE;  p.s1 = 1.0f;    p.s2 = 1.0f;
    const int nwg3 = (int)(M / 128) * (HID_ / 128);   // 256, % 8 == 0
    gemm3_mfma<<<dim3(nwg3, 3), 256, 0, stream>>>(p, (int)M, HID_, qdet);

    // attention: 256 blocks (1/CU), 32 q-rows/wave; ctx IN-PLACE into qx
    attn_mfma<<<dim3(256), 512, 0, stream>>>(qx, kx, vx, qmask, kmask, qx);

    // O-projection: 128x64 tile -> 512 blocks (2/CU)
    gemm_one<<<dim3((int)(M / 128) * (QDIM_ / 64)), 256, 0, stream>>>(
        qx, WTo, d_in[10], d_out, (int)M, QDIM_, HID_, qdet, 1.0f);
}

// Round 18
// 137.594 us; speedup vs baseline: 1.0922x; 1.0922x over previous
//
#include <hip/hip_runtime.h>
#include <hip/hip_bf16.h>

// Sizes (fixed by the problem)
#define B_   2
#define LQ_  2048
#define LK_  2048
#define QDIM_ 1024
#define KDIM_ 768
#define VDIM_ 768
#define HID_ 1024
#define H_   16
#define D_   64   // head dim

typedef unsigned short ushort_t;
typedef __attribute__((ext_vector_type(8))) short short8v;   // 8 bf16 MFMA A/B frag
typedef __attribute__((ext_vector_type(4))) float f32x4;     // MFMA C/D frag

__device__ __forceinline__ float bf2f(unsigned short u) {
    union { unsigned int i; float f; } x; x.i = ((unsigned int)u) << 16; return x.f;
}
__device__ __forceinline__ unsigned short f2bf(float f) {
    union { float f; unsigned int i; } x; x.f = f;
    unsigned int r = x.i + 0x7FFFu + ((x.i >> 16) & 1u);  // RNE
    return (unsigned short)(r >> 16);
}
__device__ __forceinline__ float exp2_(float x) {
#if defined(__has_builtin) && __has_builtin(__builtin_amdgcn_exp2f)
    return __builtin_amdgcn_exp2f(x);
#else
    return __expf(x * 0.69314718055994531f);
#endif
}
__device__ __forceinline__ unsigned cvtpk_bf16(float lo, float hi) {
    unsigned r;
    asm("v_cvt_pk_bf16_f32 %0, %1, %2" : "=v"(r) : "v"(lo), "v"(hi));
    return r;
}
__device__ __forceinline__ unsigned perm_b32(unsigned hi, unsigned lo, unsigned sel) {
#if defined(__has_builtin) && __has_builtin(__builtin_amdgcn_perm)
    return __builtin_amdgcn_perm(hi, lo, sel);
#else
    unsigned r = 0;
    for (int i = 0; i < 4; ++i) {
        unsigned s = (sel >> (8 * i)) & 0xFF;
        unsigned byte = (s < 4) ? ((lo >> (8 * s)) & 0xFF) : ((hi >> (8 * (s - 4))) & 0xFF);
        r |= byte << (8 * i);
    }
    return r;
#endif
}
// global -> LDS direct (16B per lane). Fallback: plain copy.
__device__ __forceinline__ void stage16(const ushort_t* g, ushort_t* l) {
#if defined(__has_builtin) && __has_builtin(__builtin_amdgcn_global_load_lds)
    __builtin_amdgcn_global_load_lds(
        (const __attribute__((address_space(1))) unsigned*)g,
        (__attribute__((address_space(3))) unsigned*)l, 16, 0, 0);
#else
    *(uint4*)l = *(const uint4*)g;
#endif
}

// ---------------------------------------------------------------------------
// Inline dtype detection (1 -> inputs bf16, 0 -> f32). All threads read the
// SAME 64 half-words of `query` (broadcast loads) -> block-uniform result.
// ---------------------------------------------------------------------------
__device__ __forceinline__ int detect_isbf(const ushort_t* __restrict__ q) {
    float m = 0.f;
    #pragma unroll
    for (int i = 0; i < 8; ++i) {
        uint4 v = *(const uint4*)(q + i * 8);
        const ushort_t* p = (const ushort_t*)&v;
        #pragma unroll
        for (int j = 0; j < 8; ++j) m = fmaxf(m, fabsf(bf2f(p[j])));
    }
    return m < 1000.0f ? 1 : 0;
}

// ---------------------------------------------------------------------------
// Fused 4-way transpose, 64x64 tiles, vectorized in AND out.
// op z: W[R][1024] (f32/bf16 by detection) -> WT[1024][R] bf16.
// ops: 0=Wq(R=1024) 1=Wk(768) 2=Wv(768) 3=Wo(1024)
// ---------------------------------------------------------------------------
__global__ __launch_bounds__(256) void transpose4(
    const void* __restrict__ W0, const void* __restrict__ W1,
    const void* __restrict__ W2, const void* __restrict__ W3,
    ushort_t* __restrict__ O0, ushort_t* __restrict__ O1,
    ushort_t* __restrict__ O2, ushort_t* __restrict__ O3,
    const ushort_t* __restrict__ qdet)
{
    __shared__ ushort_t tile[64][72];   // 144B rows: b128 writes aligned
    const int isbf = detect_isbf(qdet);
    const int op = blockIdx.z;
    const void* in = (op == 0) ? W0 : (op == 1) ? W1 : (op == 2) ? W2 : W3;
    ushort_t* out  = (op == 0) ? O0 : (op == 1) ? O1 : (op == 2) ? O2 : O3;
    const int R = (op == 1 || op == 2) ? KDIM_ : 1024;
    const int C = 1024;
    const int r0 = blockIdx.y * 64, c0 = blockIdx.x * 64;
    if (r0 >= R) return;
    const int tr = threadIdx.x >> 3;          // 0..31
    const int tc8 = (threadIdx.x & 7) * 8;    // 0..56

    #pragma unroll
    for (int h = 0; h < 2; ++h) {             // rows tr, tr+32
        int r = r0 + tr + h * 32;
        ushort_t tmp[8];
        if (isbf) {
            *(uint4*)tmp = *(const uint4*)((const ushort_t*)in + (size_t)r * C + c0 + tc8);
        } else {
            const float* f = (const float*)in + (size_t)r * C + c0 + tc8;
            float4 a = *(const float4*)f;
            float4 b2 = *(const float4*)(f + 4);
            tmp[0]=f2bf(a.x);  tmp[1]=f2bf(a.y);  tmp[2]=f2bf(a.z);  tmp[3]=f2bf(a.w);
            tmp[4]=f2bf(b2.x); tmp[5]=f2bf(b2.y); tmp[6]=f2bf(b2.z); tmp[7]=f2bf(b2.w);
        }
        *(uint4*)&tile[tr + h * 32][tc8] = *(uint4*)tmp;
    }
    __syncthreads();
    #pragma unroll
    for (int h = 0; h < 2; ++h) {             // out cols tr, tr+32; rows tc8..+7
        int c = tr + h * 32;
        ushort_t tmp[8];
        #pragma unroll
        for (int j = 0; j < 8; ++j) tmp[j] = tile[tc8 + j][c];
        *(uint4*)(out + (size_t)(c0 + c) * R + r0 + tc8) = *(uint4*)tmp;
    }
}

// ---------------------------------------------------------------------------
// GEMM core, 2-phase double-buffered, tile 128xTBN, BK=32, 256 thr = 4 waves
// (2x2), wave tile 64x(TBN/2). LDS XOR-swizzled (row&3 on 8-col chunks):
// pre-swizzled gload_lds source, swizzled reads.
// ---------------------------------------------------------------------------
template<int TBN>
__device__ __forceinline__ void gemm_core(
    const void* __restrict__ A, const ushort_t* __restrict__ WT,
    const void* __restrict__ bias, void* __restrict__ Cp,
    int M, int N, int K, int isbf, int a_bf, int c_bf, float out_scale,
    int wg, ushort_t (*As)[32], ushort_t (*Bs)[32])
{
    constexpr int NF = TBN / 32;              // B frags per wave
    const int tid = threadIdx.x;
    const int l = tid & 63, w = tid >> 6;
    const int g = l >> 4, q = l & 15;
    const int wr = (w >> 1) * 64, wc = (w & 1) * (TBN / 2);
    const int nbn = N / TBN;
    const int bm = (wg / nbn) * 128;
    const int bn = (wg % nbn) * TBN;

    const int r_ = tid >> 2;                    // 0..63
    const int c_ = tid & 3;                     // 8-col chunk
    const int sc_ = ((c_ ^ (r_ & 3)) << 3);     // swizzled col
    const int dc_ = c_ << 3;

    f32x4 acc[4][NF];
    #pragma unroll
    for (int i = 0; i < 4; ++i)
        #pragma unroll
        for (int j = 0; j < NF; ++j)
            acc[i][j] = (f32x4){0.f, 0.f, 0.f, 0.f};

    const int NT = K >> 5;
    float4 fA[4];

    auto issue = [&](int t, int buf) {
        const int koff = t << 5;
        if (a_bf) {
            stage16((const ushort_t*)A + (size_t)(bm + r_) * K + koff + sc_,
                    &As[(buf << 7) + r_][dc_]);
            stage16((const ushort_t*)A + (size_t)(bm + 64 + r_) * K + koff + sc_,
                    &As[(buf << 7) + 64 + r_][dc_]);
        } else {
            const float* Af0 = (const float*)A + (size_t)(bm + r_) * K + koff + dc_;
            const float* Af1 = (const float*)A + (size_t)(bm + 64 + r_) * K + koff + dc_;
            fA[0] = *(const float4*)Af0; fA[1] = *(const float4*)(Af0 + 4);
            fA[2] = *(const float4*)Af1; fA[3] = *(const float4*)(Af1 + 4);
        }
        stage16(WT + (size_t)(bn + r_) * K + koff + sc_, &Bs[buf * TBN + r_][dc_]);
        if (TBN == 128)
            stage16(WT + (size_t)(bn + 64 + r_) * K + koff + sc_, &Bs[buf * TBN + 64 + r_][dc_]);
    };
    auto commitA = [&](int buf) {
        ushort_t t0[8], t1[8];
        t0[0]=f2bf(fA[0].x); t0[1]=f2bf(fA[0].y); t0[2]=f2bf(fA[0].z); t0[3]=f2bf(fA[0].w);
        t0[4]=f2bf(fA[1].x); t0[5]=f2bf(fA[1].y); t0[6]=f2bf(fA[1].z); t0[7]=f2bf(fA[1].w);
        t1[0]=f2bf(fA[2].x); t1[1]=f2bf(fA[2].y); t1[2]=f2bf(fA[2].z); t1[3]=f2bf(fA[2].w);
        t1[4]=f2bf(fA[3].x); t1[5]=f2bf(fA[3].y); t1[6]=f2bf(fA[3].z); t1[7]=f2bf(fA[3].w);
        *(uint4*)&As[(buf << 7) + r_][sc_]      = *(uint4*)t0;
        *(uint4*)&As[(buf << 7) + 64 + r_][sc_] = *(uint4*)t1;
    };

    issue(0, 0);
    if (!a_bf) commitA(0);
    __syncthreads();

    int cur = 0;
    const int fcol = ((g ^ (q & 3)) << 3);   // frag read col (swizzled)
    for (int t = 0; t < NT; ++t) {
        const bool has = (t + 1 < NT);
        if (has) issue(t + 1, cur ^ 1);

        short8v a[4], bb[NF];
        #pragma unroll
        for (int mf = 0; mf < 4; ++mf)
            a[mf] = *(const short8v*)&As[(cur << 7) + wr + mf * 16 + q][fcol];
        #pragma unroll
        for (int nf = 0; nf < NF; ++nf)
            bb[nf] = *(const short8v*)&Bs[cur * TBN + wc + nf * 16 + q][fcol];
        #pragma unroll
        for (int mf = 0; mf < 4; ++mf)
            #pragma unroll
            for (int nf = 0; nf < NF; ++nf)
                acc[mf][nf] = __builtin_amdgcn_mfma_f32_16x16x32_bf16(a[mf], bb[nf], acc[mf][nf], 0, 0, 0);

        if (has && !a_bf) commitA(cur ^ 1);
        __syncthreads();
        cur ^= 1;
    }

    // epilogue: D layout col=lane&15, row=(lane>>4)*4+reg
    float bv[NF];
    #pragma unroll
    for (int nf = 0; nf < NF; ++nf) {
        int col = bn + wc + nf * 16 + q;
        bv[nf] = isbf ? bf2f(((const ushort_t*)bias)[col]) : ((const float*)bias)[col];
    }
    #pragma unroll
    for (int mf = 0; mf < 4; ++mf)
        #pragma unroll
        for (int nf = 0; nf < NF; ++nf)
            #pragma unroll
            for (int reg = 0; reg < 4; ++reg) {
                int row = bm + wr + mf * 16 + g * 4 + reg;
                int col = bn + wc + nf * 16 + q;
                float vv = (acc[mf][nf][reg] + bv[nf]) * out_scale;
                if (c_bf) ((ushort_t*)Cp)[(size_t)row * N + col] = f2bf(vv);
                else      ((float*)Cp)[(size_t)row * N + col] = vv;
            }
}

struct G3 {
    const void* A0; const void* A1; const void* A2;
    const ushort_t* W0; const ushort_t* W1; const ushort_t* W2;
    const void* b0; const void* b1; const void* b2;
    void* C0; void* C1; void* C2;
    int K0, K1, K2;
    float s0, s1, s2;
};

// fused Q/K/V projections: grid (256, 3); blockIdx.y picks the op
__global__ __launch_bounds__(256) void gemm3_mfma(G3 p, int M, int N,
                                                  const ushort_t* __restrict__ qdet)
{
    __shared__ ushort_t As[2 * 128][32];
    __shared__ ushort_t Bs[2 * 128][32];
    const int isbf = detect_isbf(qdet);
    const int op = blockIdx.y;
    const void* A = (op == 0) ? p.A0 : (op == 1) ? p.A1 : p.A2;
    const ushort_t* WT = (op == 0) ? p.W0 : (op == 1) ? p.W1 : p.W2;
    const void* bias = (op == 0) ? p.b0 : (op == 1) ? p.b1 : p.b2;
    void* C = (op == 0) ? p.C0 : (op == 1) ? p.C1 : p.C2;
    const int K = (op == 0) ? p.K0 : (op == 1) ? p.K1 : p.K2;
    const float sc = (op == 0) ? p.s0 : (op == 1) ? p.s1 : p.s2;
    const int cpx = gridDim.x >> 3;
    const int wg = (blockIdx.x & 7) * cpx + (blockIdx.x >> 3);
    gemm_core<128>(A, WT, bias, C, M, N, K, isbf, isbf, 1, sc, wg, As, Bs);
}

// O-projection: tile 128x64 -> 512 blocks = 2 blocks/CU
__global__ __launch_bounds__(256) void gemm_one(
    const void* __restrict__ A, const ushort_t* __restrict__ WT,
    const void* __restrict__ bias, void* __restrict__ Cp,
    int M, int N, int K, const ushort_t* __restrict__ qdet, float out_scale)
{
    __shared__ ushort_t As[2 * 128][32];
    __shared__ ushort_t Bs[2 * 64][32];
    const int isbf = detect_isbf(qdet);
    const int cpx = gridDim.x >> 3;
    const int wg = (blockIdx.x & 7) * cpx + (blockIdx.x >> 3);
    gemm_core<64>(A, WT, bias, Cp, M, N, K, isbf, 1, isbf, out_scale, wg, As, Bs);
}

// ---------------------------------------------------------------------------
// MFMA flash attention (r11-proven). 512 thr = 8 waves; block = 128 q-rows;
// KV tiles 64. Q direct to registers (no sQ). 1-D XCD-chunked grid: each XCD
// owns 4 whole (b,h) groups -> K/V L2-resident. att[2] pipeline: QK^T(t+1)
// at top of step t (K staged 2 ahead into sK[t&1]); V issue-early/write-late;
// all 32 tile masks precomputed. Swapped S^T = K.Q^T; PV O^T = V^T.P^T
// (lane-local softmax rows). Masking via packed-halfword AND on P.
// Denominator via ones-A-frag MFMA. Q pre-scaled by 0.125*log2(e).
// ctx written IN-PLACE over Q (each block writes only the slice it reads).
// query_mask masks the KEY axis; key_mask masks the QUERY axis (faithful).
// ---------------------------------------------------------------------------
__global__ __launch_bounds__(512, 4) void attn_mfma(
    const ushort_t* __restrict__ Q, const ushort_t* __restrict__ Kp,
    const ushort_t* __restrict__ Vp, const int* __restrict__ qmask,
    const int* __restrict__ kmask, ushort_t* __restrict__ ctx)   // ctx may alias Q
{
    __shared__ ushort_t sK[2][64][64];
    __shared__ ushort_t sVt[2][64][64];   // [d][key], swizzled
    __shared__ ushort_t sP[8][16][64];    // per-wave P, swizzled
    __shared__ unsigned sMaskAll[32][32]; // per-tile packed halfword masks

    const int tid = threadIdx.x;
    const int l = tid & 63, w = tid >> 6;   // 8 waves
    const int g = l >> 4, q = l & 15;
    const int wg = ((int)blockIdx.x & 7) * 64 + ((int)blockIdx.x >> 3);
    const int grp = wg >> 4;              // (b,h) group: 0..31
    const int q0 = (wg & 15) * 128;
    const int b = grp >> 4, h = grp & 15;
    const size_t hoff = (size_t)h * 64;
    const int swz = (q & 7) << 3;

    // V staging map: 256 pair-chunks (2 keys x 8 d), split across 2 threads
    const int vpi = tid & 255;
    const int vk2 = (vpi & 31) * 2;
    const int vdb = vpi >> 5;             // 0..7
    const int vds = (tid >> 8) * 4;       // 0 or 4
    const size_t vbase0 = ((size_t)(b * LK_) + vk2) * HID_ + hoff + vdb * 8 + vds;

    const int krow = tid >> 3, ks = tid & 7;
    const int kscol = ((ks ^ (krow & 7)) << 3);
    const size_t kbase0 = ((size_t)(b * LK_) + krow) * HID_ + hoff + kscol;

    auto writeV = [&](int buf, uint2 a, uint2 c) {
        #pragma unroll
        for (int t2 = 0; t2 < 2; ++t2) {
            unsigned d0w = t2 ? a.y : a.x;
            unsigned d1w = t2 ? c.y : c.x;
            unsigned lo = perm_b32(d1w, d0w, 0x05040100);
            unsigned hi = perm_b32(d1w, d0w, 0x07060302);
            int dr0 = vdb * 8 + vds + 2 * t2, dr1 = dr0 + 1;
            *(unsigned*)&sVt[buf][dr0][vk2 ^ ((dr0 & 7) << 3)] = lo;
            *(unsigned*)&sVt[buf][dr1][vk2 ^ ((dr1 & 7) << 3)] = hi;
        }
    };

    // ---- prologue: K/V tile 0, ALL 32 tile masks; Q direct to registers ----
    stage16(Kp + kbase0, &sK[0][krow][ks << 3]);
    {
        uint2 a = *(const uint2*)(Vp + vbase0);
        uint2 c = *(const uint2*)(Vp + vbase0 + HID_);
        writeV(0, a, c);
    }
    for (int tt = w; tt < 32; tt += 8) {   // each wave: 4 tiles' masks
        unsigned long long bits = __ballot(qmask[b * LQ_ + tt * 64 + l] != 0);
        if (l < 32) {
            unsigned dw = (((bits >> (2 * l)) & 1ull) ? 0xFFFFu : 0u)
                        | (((bits >> (2 * l + 1)) & 1ull) ? 0xFFFF0000u : 0u);
            sMaskAll[tt][l] = dw;
        }
    }

    const int myq = 16 * w + q;
    const ushort_t* Qrow = Q + ((size_t)(b * LQ_) + q0 + myq) * HID_ + hoff;
    short8v qf0 = *(const short8v*)(Qrow + (g << 3));
    short8v qf1 = *(const short8v*)(Qrow + 32 + (g << 3));
    const int rowm = kmask[b * LK_ + q0 + myq];
    __syncthreads();

    short8v ones;
    #pragma unroll
    for (int j = 0; j < 8; ++j) ones[j] = (short)0x3F80;   // 1.0bf16

    float m_run = -1e30f;
    f32x4 o[4], o4;
    #pragma unroll
    for (int df = 0; df < 4; ++df) o[df] = (f32x4){0.f, 0.f, 0.f, 0.f};
    o4 = (f32x4){0.f, 0.f, 0.f, 0.f};

    auto qkt = [&](int buf, f32x4 (&S)[4]) {
        #pragma unroll
        for (int kf = 0; kf < 4; ++kf) S[kf] = (f32x4){0.f, 0.f, 0.f, 0.f};
        __builtin_amdgcn_s_setprio(1);
        #pragma unroll
        for (int kf = 0; kf < 4; ++kf) {
            short8v k0f = *(const short8v*)&sK[buf][kf * 16 + q][(g << 3) ^ swz];
            short8v k1f = *(const short8v*)&sK[buf][kf * 16 + q][(32 + (g << 3)) ^ swz];
            S[kf] = __builtin_amdgcn_mfma_f32_16x16x32_bf16(k0f, qf0, S[kf], 0, 0, 0);
            S[kf] = __builtin_amdgcn_mfma_f32_16x16x32_bf16(k1f, qf1, S[kf], 0, 0, 0);
        }
        __builtin_amdgcn_s_setprio(0);
    };

    f32x4 SA[4], SB[4];
    stage16(Kp + kbase0 + (size_t)64 * HID_, &sK[1][krow][ks << 3]);
    qkt(0, SA);
    __syncthreads();

    // ---- steady state: step t = softmax+PV(t) overlapped with QK^T(t+1) ----
    auto body = [&](int t, f32x4 (&Sc)[4], f32x4 (&Sn)[4]) {
        const int nb = (t + 1) & 1;
        const bool hasN = (t + 1 < 32);
        uint2 va, vc;
        if (t + 2 < 32)
            stage16(Kp + kbase0 + (size_t)(t + 2) * 64 * HID_, &sK[t & 1][krow][ks << 3]);
        if (hasN) {
            size_t basev = vbase0 + (size_t)(t + 1) * 64 * HID_;
            va = *(const uint2*)(Vp + basev);
            vc = *(const uint2*)(Vp + basev + HID_);
            qkt(nb, Sn);
        }

        // ---- softmax(t) on Sc (raw scores; mask applied to P) ----
        float tmx[8];
        #pragma unroll
        for (int i = 0; i < 8; ++i) tmx[i] = fmaxf(Sc[i >> 2][i & 3], Sc[2 + (i >> 2)][i & 3]);
        #pragma unroll
        for (int st = 4; st >= 1; st >>= 1)
            #pragma unroll
            for (int i = 0; i < st; ++i) tmx[i] = fmaxf(tmx[i], tmx[i + st]);
        float lm = tmx[0];
        lm = fmaxf(lm, __shfl_xor(lm, 16));
        lm = fmaxf(lm, __shfl_xor(lm, 32));

        const bool fullp = __any(lm - m_run > 8.0f) != 0;   // defer-max (T13)
        float mnew, corr;
        if (fullp) { mnew = fmaxf(m_run, lm); corr = exp2_(m_run - mnew); }
        else       { mnew = m_run;            corr = 1.0f; }

        #pragma unroll
        for (int kf = 0; kf < 4; ++kf)
            #pragma unroll
            for (int reg = 0; reg < 4; ++reg)
                Sc[kf][reg] = exp2_(Sc[kf][reg] - mnew);    // P in-place
        m_run = mnew;

        #pragma unroll
        for (int kf = 0; kf < 4; ++kf) {
            uint2 pv;
            pv.x = cvtpk_bf16(Sc[kf][0], Sc[kf][1]);
            pv.y = cvtpk_bf16(Sc[kf][2], Sc[kf][3]);
            *(uint2*)&sP[w][q][(kf * 16 + g * 4) ^ swz] = pv;
        }

        if (fullp) {   // lane-local rescale (O^T layout: no shuffles)
            #pragma unroll
            for (int df = 0; df < 4; ++df)
                #pragma unroll
                for (int reg = 0; reg < 4; ++reg) o[df][reg] *= corr;
            #pragma unroll
            for (int reg = 0; reg < 4; ++reg) o4[reg] *= corr;
        }

        // ---- PV(t): O^T = V^T . P_masked^T ; denom via ones A-frag ----
        #pragma unroll
        for (int s2 = 0; s2 < 2; ++s2) {
            uint4 paw = *(const uint4*)&sP[w][q][((s2 * 32) + (g << 3)) ^ swz];
            uint4 mk = *(const uint4*)&sMaskAll[t][s2 * 16 + g * 4];
            paw.x &= mk.x; paw.y &= mk.y; paw.z &= mk.z; paw.w &= mk.w;
            short8v pa;
            __builtin_memcpy(&pa, &paw, 16);
            __builtin_amdgcn_s_setprio(1);
            #pragma unroll
            for (int df = 0; df < 4; ++df) {
                short8v vb = *(const short8v*)&sVt[t & 1][df * 16 + q][((s2 * 32) + (g << 3)) ^ swz];
                o[df] = __builtin_amdgcn_mfma_f32_16x16x32_bf16(vb, pa, o[df], 0, 0, 0);
            }
            o4 = __builtin_amdgcn_mfma_f32_16x16x32_bf16(ones, pa, o4, 0, 0, 0);
            __builtin_amdgcn_s_setprio(0);
        }

        if (hasN) writeV(nb, va, vc);   // write-late: V(t+1)
        __syncthreads();
    };

    for (int t2 = 0; t2 < 32; t2 += 2) {
        body(t2,     SA, SB);
        body(t2 + 1, SB, SA);
    }

    // ---- epilogue: outputs belong to row myq; denom lane-local in o4 ----
    const float lr = o4[0];
    const float lqv = (rowm != 0 && lr > 0.f) ? (1.f / lr) : 0.f;
    ushort_t* orow = ctx + ((size_t)(b * LQ_) + q0 + myq) * HID_ + hoff;
    #pragma unroll
    for (int df = 0; df < 4; ++df) {
        uint2 st;
        st.x = cvtpk_bf16(o[df][0] * lqv, o[df][1] * lqv);
        st.y = cvtpk_bf16(o[df][2] * lqv, o[df][3] * lqv);
        *(uint2*)(orow + df * 16 + g * 4) = st;
    }
}

// ---------------------------------------------------------------------------
extern "C" void kernel_launch(void* const* d_in, const int* in_sizes, int n_in,
                              void* d_out, int out_size, void* d_ws, size_t ws_size,
                              hipStream_t stream) {
    const int* qmask = (const int*)d_in[11];
    const int* kmask = (const int*)d_in[12];
    const ushort_t* qdet = (const ushort_t*)d_in[0];   // dtype-detection source

    const size_t M = (size_t)B_ * LQ_;      // 4096
    ushort_t* qx = (ushort_t*)((char*)d_ws + 256);   // Q-proj out, then ctx (in-place)
    ushort_t* kx = qx + M * HID_;
    ushort_t* vx = kx + M * HID_;
    ushort_t* cx = vx + M * HID_;            // 4M elems: holds ALL FOUR W^T buffers
    ushort_t* WTq = cx;                      // 1M elems
    ushort_t* WTk = WTq + 1024 * 1024;       // 0.75M
    ushort_t* WTv = WTk + 1024 * 768;        // 0.75M
    ushort_t* WTo = WTv + 1024 * 768;        // 1M  (total 3.5M <= 4M)

    const float QSCALE = 0.125f * 1.4426950408889634f;  // 1/sqrt(D) * log2(e)

    // all four weight transposes in one launch (64x64 tiles, self-detecting)
    transpose4<<<dim3(16, 16, 4), 256, 0, stream>>>(
        d_in[3], d_in[5], d_in[7], d_in[9], WTq, WTk, WTv, WTo, qdet);

    G3 p;
    p.A0 = d_in[0]; p.A1 = d_in[1]; p.A2 = d_in[2];
    p.W0 = WTq;     p.W1 = WTk;     p.W2 = WTv;
    p.b0 = d_in[4]; p.b1 = d_in[6]; p.b2 = d_in[8];
    p.C0 = qx;      p.C1 = kx;      p.C2 = vx;
    p.K0 = QDIM_;   p.K1 = KDIM_;   p.K2 = VDIM_;
    p.s0 = QSCALE;  p.s1 = 1.0f;    p.s2 = 1.0f;
    const int nwg3 = (int)(M / 128) * (HID_ / 128);   // 256, % 8 == 0
    gemm3_mfma<<<dim3(nwg3, 3), 256, 0, stream>>>(p, (int)M, HID_, qdet);

    // attention: 1-D XCD-chunked grid (512 blocks); ctx IN-PLACE into qx
    attn_mfma<<<dim3(512), 512, 0, stream>>>(qx, kx, vx, qmask, kmask, qx);

    // O-projection: 128x64 tile -> 512 blocks (2/CU)
    gemm_one<<<dim3((int)(M / 128) * (QDIM_ / 64)), 256, 0, stream>>>(
        qx, WTo, d_in[10], d_out, (int)M, QDIM_, HID_, qdet, 1.0f);
}